// Round 1
// baseline (842.515 us; speedup 1.0000x reference)
//
#include <hip/hip_runtime.h>
#include <cstdint>
#include <cstddef>

typedef unsigned int u32;
typedef unsigned short u16;

typedef __bf16 bf16x8 __attribute__((ext_vector_type(8)));
typedef float f32x4 __attribute__((ext_vector_type(4)));
typedef u32 u32x4 __attribute__((ext_vector_type(4)));
typedef float fvec4 __attribute__((ext_vector_type(4)));

#define M_DIM 4096
#define K_DIM 4096
#define N_DIM 11008

// CK-style integer round-trip casts: LDS generic addr = aperture_hi32 | offset_lo32,
// so truncation to a 32-bit AS(3) pointer yields the correct LDS offset; global
// generic and AS(1) share the same bit pattern.
#define LDS_U32(p) ((__attribute__((address_space(3))) u32*)(uintptr_t)(p))
#define GLB_CU32(p) ((const __attribute__((address_space(1))) u32*)(uintptr_t)(p))

__device__ __forceinline__ u16 f2bf(float f) {
    u32 u = __float_as_uint(f);
    u = (u + 0x7fffu + ((u >> 16) & 1u)) >> 16;   // round-to-nearest-even
    return (u16)u;
}

// ---------------- Phase 1a: x fp32 -> bf16 ----------------
__global__ __launch_bounds__(256) void convert_x_kernel(const float* __restrict__ x,
                                                        u16* __restrict__ xb) {
    size_t i = ((size_t)blockIdx.x * 256 + threadIdx.x) * 8;
    fvec4 a = *(const fvec4*)(x + i);
    fvec4 b = *(const fvec4*)(x + i + 4);
    u32x4 o;
    o.x = (u32)f2bf(a.x) | ((u32)f2bf(a.y) << 16);
    o.y = (u32)f2bf(a.z) | ((u32)f2bf(a.w) << 16);
    o.z = (u32)f2bf(b.x) | ((u32)f2bf(b.y) << 16);
    o.w = (u32)f2bf(b.z) | ((u32)f2bf(b.w) << 16);
    *(u32x4*)(xb + i) = o;
}

// ---------------- Phase 1b: dequant -> W^T bf16 [N, K] ----------------
// thread (n, kb) produces k = kb*32 .. kb*32+31 for column n (64 contiguous bytes).
__global__ __launch_bounds__(256) void dequant_kernel(const int* __restrict__ qw,
                                                      const float* __restrict__ scales,
                                                      const int* __restrict__ qz,
                                                      u16* __restrict__ wt) {
    const int n = blockIdx.x * 256 + threadIdx.x;  // grid.x = 43 -> exactly 11008
    const int kb = blockIdx.y;                     // 0..127 (32 k each)
    const int g = kb >> 2;                         // 128-sized groups, 32-aligned
    const float scale = scales[(size_t)g * N_DIM + n];
    const int z = ((qz[(size_t)g * (N_DIM / 8) + (n >> 3)] >> ((n & 7) * 4)) & 15) + 1;

    u32 packed[16];
#pragma unroll
    for (int j = 0; j < 4; ++j) {
        const int q = qw[(size_t)(kb * 4 + j) * N_DIM + n];
#pragma unroll
        for (int p = 0; p < 4; ++p) {
            const int w0 = (q >> (8 * p)) & 15;
            const int w1 = (q >> (8 * p + 4)) & 15;
            const u16 lo = f2bf(scale * (float)(w0 - z));
            const u16 hi = f2bf(scale * (float)(w1 - z));
            packed[j * 4 + p] = (u32)lo | ((u32)hi << 16);
        }
    }
    u32x4* dst = (u32x4*)(wt + (size_t)n * K_DIM + kb * 32);
#pragma unroll
    for (int j = 0; j < 4; ++j) {
        u32x4 v = {packed[j * 4 + 0], packed[j * 4 + 1], packed[j * 4 + 2], packed[j * 4 + 3]};
        dst[j] = v;
    }
}

// ---------------- Phase 2: bf16 MFMA GEMM (m97 structure) ----------------
// A [M,K] bf16 row-major; B = W^T [N,K] bf16 row-major; C [M,N] fp32 = A*B^T + bias.
// 128x128 tile, BK=32, 256 threads = 4 waves in 2x2, each wave 4x4 of 16x16x32.
__global__ __launch_bounds__(256) void gemm_kernel(const u16* __restrict__ A,
                                                   const u16* __restrict__ B,
                                                   const float* __restrict__ bias,
                                                   float* __restrict__ C) {
    __shared__ __align__(16) u16 sA[128 * 32];
    __shared__ __align__(16) u16 sB[128 * 32];

    const int tid = threadIdx.x;
    const int bn = blockIdx.x * 128;
    const int bm = blockIdx.y * 128;
    const int wave = tid >> 6;
    const int lane = tid & 63;
    const int wm = (wave >> 1) * 64;
    const int wn = (wave & 1) * 64;
    const int quad = lane >> 4;
    const int l16 = lane & 15;

    f32x4 acc[4][4];
#pragma unroll
    for (int i = 0; i < 4; ++i)
#pragma unroll
        for (int j = 0; j < 4; ++j)
            acc[i][j] = (f32x4){0.f, 0.f, 0.f, 0.f};

    // staging map: thread t loads 16B at row t/4 (0..63), k-seg (t%4)*8;
    // LDS offset = t*16 bytes (wave-uniform base + lane*16 -> global_load_lds legal)
    const int srow = tid >> 2;
    const int scol = (tid & 3) * 8;
    const u16* gA = A + (size_t)(bm + srow) * K_DIM + scol;
    const u16* gB = B + (size_t)(bn + srow) * K_DIM + scol;
    u16* lA = &sA[tid * 8];
    u16* lB = &sB[tid * 8];

    for (int k0 = 0; k0 < K_DIM; k0 += 32) {
        __syncthreads();
        __builtin_amdgcn_global_load_lds(GLB_CU32(gA + k0), LDS_U32(lA), 16, 0, 0);
        __builtin_amdgcn_global_load_lds(GLB_CU32(gA + k0 + (size_t)64 * K_DIM), LDS_U32(lA + 2048), 16, 0, 0);
        __builtin_amdgcn_global_load_lds(GLB_CU32(gB + k0), LDS_U32(lB), 16, 0, 0);
        __builtin_amdgcn_global_load_lds(GLB_CU32(gB + k0 + (size_t)64 * K_DIM), LDS_U32(lB + 2048), 16, 0, 0);
        __syncthreads();

        bf16x8 af[4], bfr[4];
#pragma unroll
        for (int i = 0; i < 4; ++i) {
            af[i]  = *(const bf16x8*)&sA[(wm + i * 16 + l16) * 32 + quad * 8];
            bfr[i] = *(const bf16x8*)&sB[(wn + i * 16 + l16) * 32 + quad * 8];
        }
#pragma unroll
        for (int i = 0; i < 4; ++i)
#pragma unroll
            for (int j = 0; j < 4; ++j)
                acc[i][j] = __builtin_amdgcn_mfma_f32_16x16x32_bf16(af[i], bfr[j], acc[i][j], 0, 0, 0);
    }

    // epilogue: C/D mapping row=(lane>>4)*4+reg, col=lane&15 (m89-verified)
    float bv[4];
#pragma unroll
    for (int j = 0; j < 4; ++j) bv[j] = bias[bn + wn + j * 16 + l16];
#pragma unroll
    for (int i = 0; i < 4; ++i) {
#pragma unroll
        for (int r = 0; r < 4; ++r) {
            const int m = bm + wm + i * 16 + quad * 4 + r;
            float* cp = C + (size_t)m * N_DIM + bn + wn + l16;
#pragma unroll
            for (int j = 0; j < 4; ++j)
                cp[j * 16] = acc[i][j][r] + bv[j];
        }
    }
}

// ---------------- Fallback (only if ws too small): fused fp32 ----------------
__global__ __launch_bounds__(256) void fused_fallback(const float* __restrict__ x,
                                                      const int* __restrict__ qw,
                                                      const float* __restrict__ scales,
                                                      const int* __restrict__ qz,
                                                      const float* __restrict__ bias,
                                                      float* __restrict__ out) {
    __shared__ float sX[32 * 128];
    const int bm = blockIdx.y * 32;   // grid.y = 128
    const int bn = blockIdx.x * 64;   // grid.x = 172
    const int tid = threadIdx.x;
    const int nl = tid & 63;
    const int n = bn + nl;
    const int mg = tid >> 6;          // 0..3, each owns 8 rows
    float acc[8] = {0, 0, 0, 0, 0, 0, 0, 0};

    for (int kt = 0; kt < K_DIM; kt += 128) {
        __syncthreads();
        for (int i = tid; i < 32 * 128; i += 256) {
            const int mm = i >> 7, kk = i & 127;
            sX[i] = x[(size_t)(bm + mm) * K_DIM + kt + kk];
        }
        __syncthreads();
        const int g = kt >> 7;
        const float scale = scales[(size_t)g * N_DIM + n];
        const int z = ((qz[(size_t)g * (N_DIM / 8) + (n >> 3)] >> ((n & 7) * 4)) & 15) + 1;
        for (int kp = 0; kp < 16; ++kp) {
            const int q = qw[(size_t)((kt >> 3) + kp) * N_DIM + n];
#pragma unroll
            for (int b = 0; b < 8; ++b) {
                const float w = scale * (float)(((q >> (4 * b)) & 15) - z);
                const int kk = kp * 8 + b;
#pragma unroll
                for (int mm = 0; mm < 8; ++mm)
                    acc[mm] += sX[(mg * 8 + mm) * 128 + kk] * w;
            }
        }
    }
#pragma unroll
    for (int mm = 0; mm < 8; ++mm)
        out[(size_t)(bm + mg * 8 + mm) * N_DIM + n] = acc[mm] + bias[n];
}

extern "C" void kernel_launch(void* const* d_in, const int* in_sizes, int n_in,
                              void* d_out, int out_size, void* d_ws, size_t ws_size,
                              hipStream_t stream) {
    const float* x      = (const float*)d_in[0];
    const int*   qw     = (const int*)d_in[1];
    const float* scales = (const float*)d_in[2];
    const int*   qz     = (const int*)d_in[3];
    // d_in[4] = g_idx: deterministic k/128, computed inline
    const float* bias   = (const float*)d_in[5];
    float* out = (float*)d_out;

    const size_t xb_bytes = (size_t)M_DIM * K_DIM * sizeof(u16);   // 33.5 MB
    const size_t wt_bytes = (size_t)N_DIM * K_DIM * sizeof(u16);   // 90.2 MB

    if (ws_size >= xb_bytes + wt_bytes) {
        u16* xb = (u16*)d_ws;
        u16* wt = (u16*)((char*)d_ws + xb_bytes);
        convert_x_kernel<<<(M_DIM * (size_t)K_DIM) / (256 * 8), 256, 0, stream>>>(x, xb);
        dequant_kernel<<<dim3(N_DIM / 256, K_DIM / 32), 256, 0, stream>>>(qw, scales, qz, wt);
        gemm_kernel<<<dim3(N_DIM / 128, M_DIM / 128), 256, 0, stream>>>(xb, wt, bias, out);
    } else {
        fused_fallback<<<dim3(N_DIM / 64, M_DIM / 32), 256, 0, stream>>>(x, qw, scales, qz, bias, out);
    }
}

// Round 2
// 689.963 us; speedup vs baseline: 1.2211x; 1.2211x over previous
//
#include <hip/hip_runtime.h>
#include <cstdint>
#include <cstddef>

typedef unsigned int u32;
typedef unsigned short u16;

typedef __bf16 bf16x8 __attribute__((ext_vector_type(8)));
typedef float f32x4 __attribute__((ext_vector_type(4)));
typedef u32 u32x4 __attribute__((ext_vector_type(4)));
typedef float fvec4 __attribute__((ext_vector_type(4)));

#define M_DIM 4096
#define K_DIM 4096
#define N_DIM 11008

// CK-style integer round-trip casts: LDS generic addr = aperture_hi32 | offset_lo32,
// so truncation to a 32-bit AS(3) pointer yields the correct LDS offset.
#define LDS_U32(p) ((__attribute__((address_space(3))) u32*)(uintptr_t)(p))
#define GLB_CU32(p) ((const __attribute__((address_space(1))) u32*)(uintptr_t)(p))

__device__ __forceinline__ u16 f2bf(float f) {
    u32 u = __float_as_uint(f);
    u = (u + 0x7fffu + ((u >> 16) & 1u)) >> 16;   // round-to-nearest-even
    return (u16)u;
}

// ---------------- Phase 1a: x fp32 -> bf16 ----------------
__global__ __launch_bounds__(256) void convert_x_kernel(const float* __restrict__ x,
                                                        u16* __restrict__ xb) {
    size_t i = ((size_t)blockIdx.x * 256 + threadIdx.x) * 8;
    fvec4 a = *(const fvec4*)(x + i);
    fvec4 b = *(const fvec4*)(x + i + 4);
    u32x4 o;
    o.x = (u32)f2bf(a.x) | ((u32)f2bf(a.y) << 16);
    o.y = (u32)f2bf(a.z) | ((u32)f2bf(a.w) << 16);
    o.z = (u32)f2bf(b.x) | ((u32)f2bf(b.y) << 16);
    o.w = (u32)f2bf(b.z) | ((u32)f2bf(b.w) << 16);
    *(u32x4*)(xb + i) = o;
}

// ---------------- Phase 1b: dequant -> W^T bf16 [N, K] ----------------
// thread (n, kb) produces k = kb*32 .. kb*32+31 for column n (64 contiguous bytes).
// Reads coalesced (lane->n consecutive); writes are full-64B-line per lane.
__global__ __launch_bounds__(256) void dequant_kernel(const int* __restrict__ qw,
                                                      const float* __restrict__ scales,
                                                      const int* __restrict__ qz,
                                                      u16* __restrict__ wt) {
    const int n = blockIdx.x * 256 + threadIdx.x;  // grid.x = 43 -> exactly 11008
    const int kb = blockIdx.y;                     // 0..127 (32 k each)
    const int g = kb >> 2;                         // 128-sized groups, 32-aligned
    const float scale = scales[(size_t)g * N_DIM + n];
    const int z = ((qz[(size_t)g * (N_DIM / 8) + (n >> 3)] >> ((n & 7) * 4)) & 15) + 1;

    u32 packed[16];
#pragma unroll
    for (int j = 0; j < 4; ++j) {
        const int q = qw[(size_t)(kb * 4 + j) * N_DIM + n];
#pragma unroll
        for (int p = 0; p < 4; ++p) {
            const int w0 = (q >> (8 * p)) & 15;
            const int w1 = (q >> (8 * p + 4)) & 15;
            const u16 lo = f2bf(scale * (float)(w0 - z));
            const u16 hi = f2bf(scale * (float)(w1 - z));
            packed[j * 4 + p] = (u32)lo | ((u32)hi << 16);
        }
    }
    u32x4* dst = (u32x4*)(wt + (size_t)n * K_DIM + kb * 32);
#pragma unroll
    for (int j = 0; j < 4; ++j) {
        u32x4 v = {packed[j * 4 + 0], packed[j * 4 + 1], packed[j * 4 + 2], packed[j * 4 + 3]};
        dst[j] = v;
    }
}

// ---------------- Phase 2: bf16 MFMA GEMM (m97 structure) ----------------
// A [M,K] bf16 row-major; B = W^T [N,K] bf16 row-major; C [M,N] fp32 = A*B^T + bias.
// 128x128 tile, BK=32, 256 threads = 4 waves in 2x2, each wave 4x4 of 16x16x32.
// Block order: grid.x = M-tiles (fast), grid.y = N-tiles -> 32 consecutive blocks
// share one 1MB B column-band; B is HBM-fetched ~once, A stays L3-resident.
__global__ __launch_bounds__(256) void gemm_kernel(const u16* __restrict__ A,
                                                   const u16* __restrict__ B,
                                                   const float* __restrict__ bias,
                                                   float* __restrict__ C) {
    __shared__ __align__(16) u16 sA[128 * 32];
    __shared__ __align__(16) u16 sB[128 * 32];

    const int tid = threadIdx.x;
    const int bm = blockIdx.x * 128;   // M-tiles fastest-varying
    const int bn = blockIdx.y * 128;   // N-tiles slow -> B col-band reuse
    const int wave = tid >> 6;
    const int lane = tid & 63;
    const int wm = (wave >> 1) * 64;
    const int wn = (wave & 1) * 64;
    const int quad = lane >> 4;
    const int l16 = lane & 15;

    f32x4 acc[4][4];
#pragma unroll
    for (int i = 0; i < 4; ++i)
#pragma unroll
        for (int j = 0; j < 4; ++j)
            acc[i][j] = (f32x4){0.f, 0.f, 0.f, 0.f};

    // staging map: thread t loads 16B at row t/4 (0..63), k-seg (t%4)*8;
    // LDS offset = t*16 bytes (wave-uniform base + lane*16 -> global_load_lds legal)
    const int srow = tid >> 2;
    const int scol = (tid & 3) * 8;
    const u16* gA = A + (size_t)(bm + srow) * K_DIM + scol;
    const u16* gB = B + (size_t)(bn + srow) * K_DIM + scol;
    u16* lA = &sA[tid * 8];
    u16* lB = &sB[tid * 8];

    for (int k0 = 0; k0 < K_DIM; k0 += 32) {
        __syncthreads();
        __builtin_amdgcn_global_load_lds(GLB_CU32(gA + k0), LDS_U32(lA), 16, 0, 0);
        __builtin_amdgcn_global_load_lds(GLB_CU32(gA + k0 + (size_t)64 * K_DIM), LDS_U32(lA + 2048), 16, 0, 0);
        __builtin_amdgcn_global_load_lds(GLB_CU32(gB + k0), LDS_U32(lB), 16, 0, 0);
        __builtin_amdgcn_global_load_lds(GLB_CU32(gB + k0 + (size_t)64 * K_DIM), LDS_U32(lB + 2048), 16, 0, 0);
        __syncthreads();

        bf16x8 af[4], bfr[4];
#pragma unroll
        for (int i = 0; i < 4; ++i) {
            af[i]  = *(const bf16x8*)&sA[(wm + i * 16 + l16) * 32 + quad * 8];
            bfr[i] = *(const bf16x8*)&sB[(wn + i * 16 + l16) * 32 + quad * 8];
        }
#pragma unroll
        for (int i = 0; i < 4; ++i)
#pragma unroll
            for (int j = 0; j < 4; ++j)
                acc[i][j] = __builtin_amdgcn_mfma_f32_16x16x32_bf16(af[i], bfr[j], acc[i][j], 0, 0, 0);
    }

    // epilogue: C/D mapping row=(lane>>4)*4+reg, col=lane&15 (m89-verified)
    float bv[4];
#pragma unroll
    for (int j = 0; j < 4; ++j) bv[j] = bias[bn + wn + j * 16 + l16];
#pragma unroll
    for (int i = 0; i < 4; ++i) {
#pragma unroll
        for (int r = 0; r < 4; ++r) {
            const int m = bm + wm + i * 16 + quad * 4 + r;
            float* cp = C + (size_t)m * N_DIM + bn + wn + l16;
#pragma unroll
            for (int j = 0; j < 4; ++j)
                cp[j * 16] = acc[i][j][r] + bv[j];
        }
    }
}

// ---------------- Fallback (only if ws too small): fused fp32 ----------------
__global__ __launch_bounds__(256) void fused_fallback(const float* __restrict__ x,
                                                      const int* __restrict__ qw,
                                                      const float* __restrict__ scales,
                                                      const int* __restrict__ qz,
                                                      const float* __restrict__ bias,
                                                      float* __restrict__ out) {
    __shared__ float sX[32 * 128];
    const int bm = blockIdx.y * 32;   // grid.y = 128
    const int bn = blockIdx.x * 64;   // grid.x = 172
    const int tid = threadIdx.x;
    const int nl = tid & 63;
    const int n = bn + nl;
    const int mg = tid >> 6;          // 0..3, each owns 8 rows
    float acc[8] = {0, 0, 0, 0, 0, 0, 0, 0};

    for (int kt = 0; kt < K_DIM; kt += 128) {
        __syncthreads();
        for (int i = tid; i < 32 * 128; i += 256) {
            const int mm = i >> 7, kk = i & 127;
            sX[i] = x[(size_t)(bm + mm) * K_DIM + kt + kk];
        }
        __syncthreads();
        const int g = kt >> 7;
        const float scale = scales[(size_t)g * N_DIM + n];
        const int z = ((qz[(size_t)g * (N_DIM / 8) + (n >> 3)] >> ((n & 7) * 4)) & 15) + 1;
        for (int kp = 0; kp < 16; ++kp) {
            const int q = qw[(size_t)((kt >> 3) + kp) * N_DIM + n];
#pragma unroll
            for (int b = 0; b < 8; ++b) {
                const float w = scale * (float)(((q >> (4 * b)) & 15) - z);
                const int kk = kp * 8 + b;
#pragma unroll
                for (int mm = 0; mm < 8; ++mm)
                    acc[mm] += sX[(mg * 8 + mm) * 128 + kk] * w;
            }
        }
    }
#pragma unroll
    for (int mm = 0; mm < 8; ++mm)
        out[(size_t)(bm + mg * 8 + mm) * N_DIM + n] = acc[mm] + bias[n];
}

extern "C" void kernel_launch(void* const* d_in, const int* in_sizes, int n_in,
                              void* d_out, int out_size, void* d_ws, size_t ws_size,
                              hipStream_t stream) {
    const float* x      = (const float*)d_in[0];
    const int*   qw     = (const int*)d_in[1];
    const float* scales = (const float*)d_in[2];
    const int*   qz     = (const int*)d_in[3];
    // d_in[4] = g_idx: deterministic k/128, computed inline
    const float* bias   = (const float*)d_in[5];
    float* out = (float*)d_out;

    const size_t xb_bytes = (size_t)M_DIM * K_DIM * sizeof(u16);   // 33.5 MB
    const size_t wt_bytes = (size_t)N_DIM * K_DIM * sizeof(u16);   // 90.2 MB

    if (ws_size >= xb_bytes + wt_bytes) {
        u16* xb = (u16*)d_ws;
        u16* wt = (u16*)((char*)d_ws + xb_bytes);
        convert_x_kernel<<<(M_DIM * (size_t)K_DIM) / (256 * 8), 256, 0, stream>>>(x, xb);
        dequant_kernel<<<dim3(N_DIM / 256, K_DIM / 32), 256, 0, stream>>>(qw, scales, qz, wt);
        // M-tiles fastest (x), N-tiles slow (y): B column-band reuse in L2/L3
        gemm_kernel<<<dim3(M_DIM / 128, N_DIM / 128), 256, 0, stream>>>(xb, wt, bias, out);
    } else {
        fused_fallback<<<dim3(N_DIM / 64, M_DIM / 32), 256, 0, stream>>>(x, qw, scales, qz, bias, out);
    }
}

// Round 3
// 686.595 us; speedup vs baseline: 1.2271x; 1.0049x over previous
//
#include <hip/hip_runtime.h>
#include <cstdint>
#include <cstddef>

typedef unsigned int u32;
typedef unsigned short u16;

typedef __bf16 bf16x8 __attribute__((ext_vector_type(8)));
typedef float f32x4 __attribute__((ext_vector_type(4)));
typedef u32 u32x2 __attribute__((ext_vector_type(2)));
typedef u32 u32x4 __attribute__((ext_vector_type(4)));
typedef float fvec4 __attribute__((ext_vector_type(4)));

#define M_DIM 4096
#define K_DIM 4096
#define N_DIM 11008

// CK-style integer round-trip casts: LDS generic addr = aperture_hi32 | offset_lo32,
// so truncation to a 32-bit AS(3) pointer yields the correct LDS offset.
#define LDS_U32(p) ((__attribute__((address_space(3))) u32*)(uintptr_t)(p))
#define GLB_CU32(p) ((const __attribute__((address_space(1))) u32*)(uintptr_t)(p))

__device__ __forceinline__ u16 f2bf(float f) {
    u32 u = __float_as_uint(f);
    u = (u + 0x7fffu + ((u >> 16) & 1u)) >> 16;   // round-to-nearest-even
    return (u16)u;
}

// ---------------- Phase 1a: x fp32 -> bf16 ----------------
__global__ __launch_bounds__(256) void convert_x_kernel(const float* __restrict__ x,
                                                        u16* __restrict__ xb) {
    size_t i = ((size_t)blockIdx.x * 256 + threadIdx.x) * 8;
    fvec4 a = *(const fvec4*)(x + i);
    fvec4 b = *(const fvec4*)(x + i + 4);
    u32x4 o;
    o.x = (u32)f2bf(a.x) | ((u32)f2bf(a.y) << 16);
    o.y = (u32)f2bf(a.z) | ((u32)f2bf(a.w) << 16);
    o.z = (u32)f2bf(b.x) | ((u32)f2bf(b.y) << 16);
    o.w = (u32)f2bf(b.z) | ((u32)f2bf(b.w) << 16);
    *(u32x4*)(xb + i) = o;
}

// ---------------- Phase 1b: dequant -> W^T bf16 [N, K], LDS-transposed ----------------
// Block tile: 64 n x 128 k (k-tile == GROUPSIZE, so one (g) per block).
// Phase A (unpack): thread = (n_sub = tid&63, kc = tid>>6); reads 4 qweight words
//   (lane->n consecutive => 256B coalesced), unpacks 32 bf16 into LDS row n_sub.
//   LDS row stride 132 u16 = 66 dwords => write banks = 2*n mod 32, 2-way (free, m136).
// Phase B (write-out): lanes cover (4 rows x 16 k-segs of 16B) => each store inst
//   writes 4 contiguous 256B runs instead of 64 scattered 16B chunks (R2's bound).
__global__ __launch_bounds__(256) void dequant_kernel(const int* __restrict__ qw,
                                                      const float* __restrict__ scales,
                                                      const int* __restrict__ qz,
                                                      u16* __restrict__ wt) {
    __shared__ __align__(16) u16 sT[64][132];

    const int tid = threadIdx.x;
    const int n0 = blockIdx.x * 64;   // grid.x = 172 -> exactly 11008
    const int g = blockIdx.y;         // grid.y = 32; k-tile = g*128 .. +127
    const int n_sub = tid & 63;
    const int kc = tid >> 2 >> 4;     // tid >> 6: 0..3, 32 k each
    const int n = n0 + n_sub;

    const float scale = scales[(size_t)g * N_DIM + n];
    const int z = ((qz[(size_t)g * (N_DIM / 8) + (n >> 3)] >> ((n & 7) * 4)) & 15) + 1;

#pragma unroll
    for (int j = 0; j < 4; ++j) {
        const int q = qw[(size_t)(g * 16 + kc * 4 + j) * N_DIM + n];
        u32 a[4];
#pragma unroll
        for (int p = 0; p < 4; ++p) {
            const int w0 = (q >> (8 * p)) & 15;
            const int w1 = (q >> (8 * p + 4)) & 15;
            a[p] = (u32)f2bf(scale * (float)(w0 - z)) |
                   ((u32)f2bf(scale * (float)(w1 - z)) << 16);
        }
        // row base is 8B-aligned (264B stride); chunk offset 16B-aligned -> two b64 stores
        u32x2* dst = (u32x2*)&sT[n_sub][kc * 32 + j * 8];
        dst[0] = (u32x2){a[0], a[1]};
        dst[1] = (u32x2){a[2], a[3]};
    }

    __syncthreads();

    // write-out: thread (r = it*16 + tid/16, c = tid&15) stores 16B of row r
    const int c = tid & 15;
#pragma unroll
    for (int it = 0; it < 4; ++it) {
        const int r = it * 16 + (tid >> 4);
        const u32x2* src = (const u32x2*)&sT[r][c * 8];
        u32x4 v = {src[0].x, src[0].y, src[1].x, src[1].y};
        *(u32x4*)(wt + (size_t)(n0 + r) * K_DIM + g * 128 + c * 8) = v;
    }
}

// ---------------- Phase 2: bf16 MFMA GEMM (m97 structure) ----------------
// A [M,K] bf16 row-major; B = W^T [N,K] bf16 row-major; C [M,N] fp32 = A*B^T + bias.
// 128x128 tile, BK=32, 256 threads = 4 waves in 2x2, each wave 4x4 of 16x16x32.
// Block order: grid.x = M-tiles (fast), grid.y = N-tiles -> 32 consecutive blocks
// share one 1MB B column-band; B is HBM-fetched ~once, A stays L3-resident.
__global__ __launch_bounds__(256) void gemm_kernel(const u16* __restrict__ A,
                                                   const u16* __restrict__ B,
                                                   const float* __restrict__ bias,
                                                   float* __restrict__ C) {
    __shared__ __align__(16) u16 sA[128 * 32];
    __shared__ __align__(16) u16 sB[128 * 32];

    const int tid = threadIdx.x;
    const int bm = blockIdx.x * 128;   // M-tiles fastest-varying
    const int bn = blockIdx.y * 128;   // N-tiles slow -> B col-band reuse
    const int wave = tid >> 6;
    const int lane = tid & 63;
    const int wm = (wave >> 1) * 64;
    const int wn = (wave & 1) * 64;
    const int quad = lane >> 4;
    const int l16 = lane & 15;

    f32x4 acc[4][4];
#pragma unroll
    for (int i = 0; i < 4; ++i)
#pragma unroll
        for (int j = 0; j < 4; ++j)
            acc[i][j] = (f32x4){0.f, 0.f, 0.f, 0.f};

    // staging map: thread t loads 16B at row t/4 (0..63), k-seg (t%4)*8;
    // LDS offset = t*16 bytes (wave-uniform base + lane*16 -> global_load_lds legal)
    const int srow = tid >> 2;
    const int scol = (tid & 3) * 8;
    const u16* gA = A + (size_t)(bm + srow) * K_DIM + scol;
    const u16* gB = B + (size_t)(bn + srow) * K_DIM + scol;
    u16* lA = &sA[tid * 8];
    u16* lB = &sB[tid * 8];

    for (int k0 = 0; k0 < K_DIM; k0 += 32) {
        __syncthreads();
        __builtin_amdgcn_global_load_lds(GLB_CU32(gA + k0), LDS_U32(lA), 16, 0, 0);
        __builtin_amdgcn_global_load_lds(GLB_CU32(gA + k0 + (size_t)64 * K_DIM), LDS_U32(lA + 2048), 16, 0, 0);
        __builtin_amdgcn_global_load_lds(GLB_CU32(gB + k0), LDS_U32(lB), 16, 0, 0);
        __builtin_amdgcn_global_load_lds(GLB_CU32(gB + k0 + (size_t)64 * K_DIM), LDS_U32(lB + 2048), 16, 0, 0);
        __syncthreads();

        bf16x8 af[4], bfr[4];
#pragma unroll
        for (int i = 0; i < 4; ++i) {
            af[i]  = *(const bf16x8*)&sA[(wm + i * 16 + l16) * 32 + quad * 8];
            bfr[i] = *(const bf16x8*)&sB[(wn + i * 16 + l16) * 32 + quad * 8];
        }
#pragma unroll
        for (int i = 0; i < 4; ++i)
#pragma unroll
            for (int j = 0; j < 4; ++j)
                acc[i][j] = __builtin_amdgcn_mfma_f32_16x16x32_bf16(af[i], bfr[j], acc[i][j], 0, 0, 0);
    }

    // epilogue: C/D mapping row=(lane>>4)*4+reg, col=lane&15 (m89-verified)
    float bv[4];
#pragma unroll
    for (int j = 0; j < 4; ++j) bv[j] = bias[bn + wn + j * 16 + l16];
#pragma unroll
    for (int i = 0; i < 4; ++i) {
#pragma unroll
        for (int r = 0; r < 4; ++r) {
            const int m = bm + wm + i * 16 + quad * 4 + r;
            float* cp = C + (size_t)m * N_DIM + bn + wn + l16;
#pragma unroll
            for (int j = 0; j < 4; ++j)
                cp[j * 16] = acc[i][j][r] + bv[j];
        }
    }
}

// ---------------- Fallback (only if ws too small): fused fp32 ----------------
__global__ __launch_bounds__(256) void fused_fallback(const float* __restrict__ x,
                                                      const int* __restrict__ qw,
                                                      const float* __restrict__ scales,
                                                      const int* __restrict__ qz,
                                                      const float* __restrict__ bias,
                                                      float* __restrict__ out) {
    __shared__ float sX[32 * 128];
    const int bm = blockIdx.y * 32;   // grid.y = 128
    const int bn = blockIdx.x * 64;   // grid.x = 172
    const int tid = threadIdx.x;
    const int nl = tid & 63;
    const int n = bn + nl;
    const int mg = tid >> 6;          // 0..3, each owns 8 rows
    float acc[8] = {0, 0, 0, 0, 0, 0, 0, 0};

    for (int kt = 0; kt < K_DIM; kt += 128) {
        __syncthreads();
        for (int i = tid; i < 32 * 128; i += 256) {
            const int mm = i >> 7, kk = i & 127;
            sX[i] = x[(size_t)(bm + mm) * K_DIM + kt + kk];
        }
        __syncthreads();
        const int g = kt >> 7;
        const float scale = scales[(size_t)g * N_DIM + n];
        const int z = ((qz[(size_t)g * (N_DIM / 8) + (n >> 3)] >> ((n & 7) * 4)) & 15) + 1;
        for (int kp = 0; kp < 16; ++kp) {
            const int q = qw[(size_t)((kt >> 3) + kp) * N_DIM + n];
#pragma unroll
            for (int b = 0; b < 8; ++b) {
                const float w = scale * (float)(((q >> (4 * b)) & 15) - z);
                const int kk = kp * 8 + b;
#pragma unroll
                for (int mm = 0; mm < 8; ++mm)
                    acc[mm] += sX[(mg * 8 + mm) * 128 + kk] * w;
            }
        }
    }
#pragma unroll
    for (int mm = 0; mm < 8; ++mm)
        out[(size_t)(bm + mg * 8 + mm) * N_DIM + n] = acc[mm] + bias[n];
}

extern "C" void kernel_launch(void* const* d_in, const int* in_sizes, int n_in,
                              void* d_out, int out_size, void* d_ws, size_t ws_size,
                              hipStream_t stream) {
    const float* x      = (const float*)d_in[0];
    const int*   qw     = (const int*)d_in[1];
    const float* scales = (const float*)d_in[2];
    const int*   qz     = (const int*)d_in[3];
    // d_in[4] = g_idx: deterministic k/128, computed inline
    const float* bias   = (const float*)d_in[5];
    float* out = (float*)d_out;

    const size_t xb_bytes = (size_t)M_DIM * K_DIM * sizeof(u16);   // 33.5 MB
    const size_t wt_bytes = (size_t)N_DIM * K_DIM * sizeof(u16);   // 90.2 MB

    if (ws_size >= xb_bytes + wt_bytes) {
        u16* xb = (u16*)d_ws;
        u16* wt = (u16*)((char*)d_ws + xb_bytes);
        convert_x_kernel<<<(M_DIM * (size_t)K_DIM) / (256 * 8), 256, 0, stream>>>(x, xb);
        dequant_kernel<<<dim3(N_DIM / 64, K_DIM / 128), 256, 0, stream>>>(qw, scales, qz, wt);
        // M-tiles fastest (x), N-tiles slow (y): B column-band reuse in L2/L3
        gemm_kernel<<<dim3(M_DIM / 128, N_DIM / 128), 256, 0, stream>>>(xb, wt, bias, out);
    } else {
        fused_fallback<<<dim3(N_DIM / 64, M_DIM / 32), 256, 0, stream>>>(x, qw, scales, qz, bias, out);
    }
}